// Round 17
// baseline (600.994 us; speedup 1.0000x reference)
//
#include <hip/hip_runtime.h>

// Decoder, B=16, T=64, S=128, D_ENC=512, U=256, V=32000.
// Round 17: (a) wdtile merged into the prologue launch; (b) p-exchange
// deleted — scores computed fully in-block (4-way u-split, 64 tanh/thread),
// softmax entirely in LDS. Only the h-exchange crosses blocks per step.
// mega: XCD 0-3 producers / XCD 4-7 consumers (reg-held acc, 1 MFMA pass).

#define NB 16
#define NT 64
#define NS 128
#define DE 512
#define NU 256
#define NV 32000

// ws layout (floats); total 30.7 MB (<= 34.5 MB proven in R2)
static const size_t OFF_KEYS  = 0;          // keysT bf16 [16][256][128] -> 262144
static const size_t OFF_HX    = 262144;     // hx dbuf [2][16][256] (sign-tag,+2)
static const size_t OFF_RS    = 274432;     // rowsums [1024]
static const size_t OFF_CNT   = 275456;     // pdone[8] @0, done0[8] @32 (128 ints)
static const size_t OFF_HB    = 275584;     // Hb fragment-tiled bf16 -> 131072 fl
static const size_t OFF_W1P   = 406656;     // W1 f16-packed -> 32768
static const size_t OFF_ENCWX = 439424;     // [2048][1024] fp32 -> 2097152
static const size_t OFF_ZEMB  = 2536576;    // [1024][1024] fp32 -> 1048576
static const size_t OFF_WDT   = 3585152;    // wdT bf16 tiled -> 4096000 fl

typedef __attribute__((ext_vector_type(8))) short bf16x8;
typedef __attribute__((ext_vector_type(4))) float f32x4;
typedef __attribute__((ext_vector_type(2))) _Float16 f16x2;

__device__ __forceinline__ float bf2f(unsigned int us) { return __uint_as_float(us << 16); }
__device__ __forceinline__ unsigned short f2bf(float f) {
    unsigned int u = __float_as_uint(f);
    return (unsigned short)((u + 0x7fffu + ((u >> 16) & 1u)) >> 16);
}
__device__ __forceinline__ float rcp_fast(float x) { return __builtin_amdgcn_rcpf(x); }
__device__ __forceinline__ float sigm(float x) { return rcp_fast(1.0f + __expf(-x)); }
__device__ __forceinline__ float tanh1(float x) {
    float e = __expf(2.0f * x);
    return 1.0f - 2.0f * rcp_fast(e + 1.0f);
}
__device__ __forceinline__ void cstore(float* p, float v) {
    __hip_atomic_store(p, v, __ATOMIC_RELAXED, __HIP_MEMORY_SCOPE_AGENT);
}
__device__ __forceinline__ float cload(const float* p) {
    return __hip_atomic_load(p, __ATOMIC_RELAXED, __HIP_MEMORY_SCOPE_AGENT);
}
__device__ __forceinline__ unsigned long long cload_ull(const unsigned long long* p) {
    return __hip_atomic_load(p, __ATOMIC_RELAXED, __HIP_MEMORY_SCOPE_AGENT);
}
__device__ __forceinline__ int cload_i(const int* p) {
    return __hip_atomic_load(p, __ATOMIC_RELAXED, __HIP_MEMORY_SCOPE_AGENT);
}

#if __has_builtin(__builtin_amdgcn_fdot2)
__device__ __forceinline__ float dot2(f16x2 w, f16x2 h, float a) {
    return __builtin_amdgcn_fdot2(w, h, a, false);
}
#else
__device__ __forceinline__ float dot2(f16x2 w, f16x2 h, float a) {
    return fmaf((float)w.x, (float)h.x, fmaf((float)w.y, (float)h.y, a));
}
#endif

__device__ __forceinline__ float poll_tagged(const float* p, unsigned tag) {
    float raw = cload(p);
    while ((__float_as_uint(raw) >> 31) != tag) {
        __builtin_amdgcn_s_sleep(1);
        raw = cload(p);
    }
    return __builtin_fabsf(raw);
}

// ---------------- fused prologue (+ wdtile) — one launch ----------------
__launch_bounds__(256)
__global__ void prologue_kernel(const int* __restrict__ dec, const float* __restrict__ enc,
                                const float* __restrict__ emb, const float* __restrict__ W1,
                                const float* __restrict__ W2, const float* __restrict__ b2,
                                const float* __restrict__ Wx, const float* __restrict__ b_lstm,
                                const float* __restrict__ Wd,
                                float* __restrict__ rs, int* __restrict__ cnt,
                                float* __restrict__ hx,
                                unsigned int* __restrict__ W1h, unsigned short* __restrict__ keysT,
                                float* __restrict__ encWx, float* __restrict__ zemb,
                                unsigned short* __restrict__ wdT) {
    int blk = blockIdx.x, tid = threadIdx.x;
    if (blk < 4) {
        int i = blk * 256 + tid;
        rs[i] = 0.f;
        if (i < 128) cnt[i] = 0;
    } else if (blk < 36) {
        // hx sentinels: slot0 = +2, slot1 = -2
        int idx = (blk - 4) * 256 + tid;
        hx[idx] = (idx < 4096) ? 2.0f : -2.0f;
    } else if (blk < 164) {
        int id = (blk - 36) * 256 + tid;
        int dp = id >> 8, u = id & 255;
        unsigned short lo = __builtin_bit_cast(unsigned short, (_Float16)W1[(size_t)(2 * dp) * NU + u]);
        unsigned short hi = __builtin_bit_cast(unsigned short, (_Float16)W1[(size_t)(2 * dp + 1) * NU + u]);
        W1h[id] = (unsigned int)lo | ((unsigned int)hi << 16);
    } else if (blk < 292) {
        int bb = (blk - 164) >> 3, sg = (blk - 164) & 7;
        int u = tid;
        float acc[16];
        float bias = b2[u];
#pragma unroll
        for (int r = 0; r < 16; r++) acc[r] = bias;
        const float4* e4 = (const float4*)(enc + ((size_t)bb * NS + sg * 16) * DE);
        const float* wp = W2 + u;
        for (int k4 = 0; k4 < DE / 4; k4++) {
            float w0 = wp[(size_t)(k4 * 4 + 0) * NU];
            float w1 = wp[(size_t)(k4 * 4 + 1) * NU];
            float w2v = wp[(size_t)(k4 * 4 + 2) * NU];
            float w3v = wp[(size_t)(k4 * 4 + 3) * NU];
#pragma unroll
            for (int r = 0; r < 16; r++) {
                float4 e = e4[(size_t)r * (DE / 4) + k4];  // wave-uniform
                acc[r] = fmaf(e.x, w0, fmaf(e.y, w1, fmaf(e.z, w2v, fmaf(e.w, w3v, acc[r]))));
            }
        }
        unsigned int ow[8];
#pragma unroll
        for (int i = 0; i < 8; i++)
            ow[i] = (unsigned int)f2bf(acc[2 * i]) | ((unsigned int)f2bf(acc[2 * i + 1]) << 16);
        uint4* dst = (uint4*)(keysT + ((size_t)bb * NU + u) * NS + sg * 16);
        dst[0] = make_uint4(ow[0], ow[1], ow[2], ow[3]);
        dst[1] = make_uint4(ow[4], ow[5], ow[6], ow[7]);
    } else if (blk < 804) {
        int rg = (blk - 292) >> 2, jq = (blk - 292) & 3;
        int j = jq * 256 + tid;
        float acc[16];
#pragma unroll
        for (int r = 0; r < 16; r++) acc[r] = 0.f;
        const float4* e4 = (const float4*)(enc + (size_t)rg * 16 * DE);
        const float* wp = Wx + j;
        for (int k4 = 0; k4 < DE / 4; k4++) {
            float w0 = wp[(size_t)(k4 * 4 + 0) * 1024];
            float w1 = wp[(size_t)(k4 * 4 + 1) * 1024];
            float w2v = wp[(size_t)(k4 * 4 + 2) * 1024];
            float w3v = wp[(size_t)(k4 * 4 + 3) * 1024];
#pragma unroll
            for (int r = 0; r < 16; r++) {
                float4 e = e4[(size_t)r * (DE / 4) + k4];  // wave-uniform
                acc[r] = fmaf(e.x, w0, fmaf(e.y, w1, fmaf(e.z, w2v, fmaf(e.w, w3v, acc[r]))));
            }
        }
#pragma unroll
        for (int r = 0; r < 16; r++) encWx[(size_t)(rg * 16 + r) * 1024 + j] = acc[r];
    } else if (blk < 1060) {
        int rg = (blk - 804) >> 2, jq = (blk - 804) & 3;
        int j = jq * 256 + tid;
        int tokr[16];
#pragma unroll
        for (int r = 0; r < 16; r++) {
            int row = rg * 16 + r;
            int tok = dec[(row >> 6) * NT + (row & 63)];
            tokr[r] = (tok < 0) ? 0 : (tok >= NV ? NV - 1 : tok);
        }
        float acc[16];
        float bias = b_lstm[j];
#pragma unroll
        for (int r = 0; r < 16; r++) acc[r] = bias;
        const float* wp = Wx + (size_t)512 * 1024 + j;
        for (int k4 = 0; k4 < NU / 4; k4++) {
            float w0 = wp[(size_t)(k4 * 4 + 0) * 1024];
            float w1 = wp[(size_t)(k4 * 4 + 1) * 1024];
            float w2v = wp[(size_t)(k4 * 4 + 2) * 1024];
            float w3v = wp[(size_t)(k4 * 4 + 3) * 1024];
#pragma unroll
            for (int r = 0; r < 16; r++) {
                float4 e = ((const float4*)(emb + (size_t)tokr[r] * NU))[k4];  // uniform
                acc[r] = fmaf(e.x, w0, fmaf(e.y, w1, fmaf(e.z, w2v, fmaf(e.w, w3v, acc[r]))));
            }
        }
#pragma unroll
        for (int r = 0; r < 16; r++) zemb[(size_t)(rg * 16 + r) * 1024 + j] = acc[r];
    } else {
        // wdtile: Wd -> fragment-tiled bf16
        int id = (blk - 1060) * 256 + tid;
        int l = id & 63, c16 = (id >> 6) & 7, ks = (id >> 9) & 7, p = id >> 12;
        int v = p * 128 + c16 * 16 + (l & 15);
        int k0 = ks * 32 + (l >> 4) * 8;
        unsigned int wout[4];
#pragma unroll
        for (int jj = 0; jj < 4; jj++) {
            unsigned int lo = f2bf(Wd[(size_t)(k0 + 2 * jj) * NV + v]);
            unsigned int hi = f2bf(Wd[(size_t)(k0 + 2 * jj + 1) * NV + v]);
            wout[jj] = lo | (hi << 16);
        }
        *(uint4*)(wdT + (size_t)id * 8) = make_uint4(wout[0], wout[1], wout[2], wout[3]);
    }
}

// ---------------- mega: XCD 0-3 producers, XCD 4-7 consumers ----------------
__launch_bounds__(512, 2)
__global__ void mega_kernel(const float* __restrict__ b1, const float* __restrict__ Va,
                            const float* __restrict__ bV, const float* __restrict__ Wh,
                            const float* __restrict__ h0, const float* __restrict__ c0,
                            const unsigned short* __restrict__ keysT,
                            const unsigned int* __restrict__ W1h,
                            const float* __restrict__ encWx, const float* __restrict__ zemb,
                            float* __restrict__ hx, unsigned short* __restrict__ Hb,
                            const unsigned short* __restrict__ wdT,
                            const float* __restrict__ bd, float* __restrict__ rs,
                            int* __restrict__ cnt, float* __restrict__ out) {
    __shared__ float smem[21504];  // 86 KB: forces 1 block/CU
    int tid = threadIdx.x;
    int blk = blockIdx.x;
    int xcd = blk & 7;
    int slot = blk >> 3;
    int* pdone = cnt;        // [8]
    int* done0 = cnt + 32;   // [8]

    if (xcd < 4) {
        // ================= producer: recurrence gang (XCDs 0-3) =================
        int b = (slot >> 3) * 4 + xcd;   // gang = batch, XCD-local
        int r = slot & 7;

        float* hl = smem;
        _Float16* hf = (_Float16*)(smem + 256);
        float* qred = smem + 384;
        float* qv = smem + 896;
        float* scp = smem + 1152;   // 512 score partials
        float* attnp = smem + 1664; // 128 raw p
        float* zred = smem + 1792;  // 512

        int kg = tid >> 7, jl = tid & 127;
        int g = jl >> 5, i32 = jl & 31;
        int j = g * 256 + r * 32 + i32;

        float bV0 = bV[0];
        float c_reg = (tid < 32) ? c0[b * NU + r * 32 + tid] : 0.f;

        float wreg[96];
        {
            const float* ew = encWx + (size_t)b * 128 * 1024 + j;
            const float* wh = Wh + j;
#pragma unroll
            for (int kk = 0; kk < 96; kk++) {
                int k = kg * 96 + kk;
                wreg[kk] = (k < 128) ? ew[(size_t)k * 1024] : wh[(size_t)(k - 128) * 1024];
            }
        }

        for (int it = 0; it < NT; ++it) {
            unsigned tag = (unsigned)((it >> 1) & 1);
            float zpre4[4];
            if (tid < 32) {
#pragma unroll
                for (int gg = 0; gg < 4; gg++)
                    zpre4[gg] = zemb[((size_t)b * NT + it) * 1024 + gg * 256 + r * 32 + tid];
            }
            if (tid < NU) {
                float hv;
                if (it == 0) {
                    hv = h0[b * NU + tid];
                } else {
                    hv = poll_tagged(hx + (size_t)(it & 1) * 4096 + b * NU + tid, tag) - 2.0f;
                }
                hl[tid] = hv;
                hf[tid] = (_Float16)hv;
            }
            __syncthreads();  // S1

            // q = h @ W1 (f16 dot2)
            {
                int u0 = tid & 255, dh = tid >> 8;
                const unsigned int* wp = W1h + dh * 64 * 256 + u0;
                const f16x2* hp = (const f16x2*)hf + dh * 64;
                float a = 0.f;
#pragma unroll 8
                for (int dp = 0; dp < 64; dp++) {
                    f16x2 wv = __builtin_bit_cast(f16x2, wp[(size_t)dp * 256]);
                    a = dot2(wv, hp[dp], a);
                }
                qred[dh * 256 + u0] = a;
            }
            __syncthreads();  // S2
            if (tid < NU) qv[tid] = qred[tid] + qred[256 + tid] + b1[tid];
            __syncthreads();  // S3

            // scores: ALL 128 s in-block; thread = (s:128, uc:4 x 64u)
            {
                int s = tid & 127, uc = tid >> 7;
                const unsigned short* kp = keysT + ((size_t)b * NU + uc * 64) * NS + s;
                float sc = 0.f;
#pragma unroll 4
                for (int i = 0; i < 64; i++)
                    sc = fmaf(tanh1(qv[uc * 64 + i] + bf2f(kp[(size_t)i * NS])),
                              Va[uc * 64 + i], sc);
                scp[uc * 128 + s] = sc;
            }
            __syncthreads();  // S4
            if (tid < 128) {
                float sum = scp[tid] + scp[128 + tid] + scp[256 + tid] + scp[384 + tid] + bV0;
                attnp[tid] = __expf(sum);
            }
            __syncthreads();  // S5
            // tot: per-wave shfl reduce (all waves redundantly)
            float tot;
            {
                int lane = tid & 63;
                float v = attnp[lane] + attnp[64 + lane];
#pragma unroll
                for (int off = 32; off >= 1; off >>= 1) v += __shfl_xor(v, off, 64);
                tot = v;
            }
            // z slice: 96 register-weight FMAs
            float aA = 0.f, aH = 0.f;
            if (kg == 0) {
#pragma unroll
                for (int kk = 0; kk < 96; kk++) aA = fmaf(wreg[kk], attnp[kk], aA);
            } else if (kg == 1) {
#pragma unroll
                for (int kk = 0; kk < 32; kk++) aA = fmaf(wreg[kk], attnp[96 + kk], aA);
#pragma unroll
                for (int kk = 32; kk < 96; kk++) aH = fmaf(wreg[kk], hl[kk - 32], aH);
            } else {
                int base = kg * 96 - 128;
#pragma unroll
                for (int kk = 0; kk < 96; kk++) aH = fmaf(wreg[kk], hl[base + kk], aH);
            }
            zred[kg * 128 + jl] = aA * rcp_fast(tot) + aH;
            __syncthreads();  // S6

            if (tid < 32) {
                float z4[4];
#pragma unroll
                for (int gg = 0; gg < 4; gg++) {
                    int jj = gg * 32 + tid;
                    z4[gg] = zred[jj] + zred[128 + jj] + zred[256 + jj] + zred[384 + jj] + zpre4[gg];
                }
                float cn = sigm(z4[1]) * c_reg + sigm(z4[0]) * tanh1(z4[2]);
                c_reg = cn;
                float hn = sigm(z4[3]) * tanh1(cn);
                int u = r * 32 + tid;
                int rr = it * NB + b;
                int mp = rr >> 7, lr = rr & 127;
                int chunk = ((u >> 5) * 8 + (lr >> 4)) * 64 + ((u >> 3) & 3) * 16 + (lr & 15);
                __hip_atomic_store(&Hb[(size_t)mp * 32768 + chunk * 8 + (u & 7)], f2bf(hn),
                                   __ATOMIC_RELAXED, __HIP_MEMORY_SCOPE_AGENT);
                unsigned ntag = (unsigned)(((it + 1) >> 1) & 1);
                float enc2 = hn + 2.0f;
                cstore(hx + (size_t)((it + 1) & 1) * 4096 + b * NU + u, ntag ? -enc2 : enc2);
            }
            if ((it & 7) == 7 && tid < 64) {
                asm volatile("s_waitcnt vmcnt(0)" ::: "memory");
                if (tid == 0)
                    __hip_atomic_fetch_add(pdone + (it >> 3), 1, __ATOMIC_RELAXED,
                                           __HIP_MEMORY_SCOPE_AGENT);
            }
        }
    } else {
        // ================= consumer: vocab GEMM (XCDs 4-7) =================
        int c = slot * 4 + (xcd - 4);  // 0..127
        float* ldsA = smem;            // 64 KB A panel
        float* sums = smem + 16384;    // [128][4]
        const unsigned long long* HbU = (const unsigned long long*)Hb;
        unsigned long long* ldsU = (unsigned long long*)ldsA;

        int wave = tid >> 6, l = tid & 63;
        int wm = wave >> 2, wn = wave & 3;
        int nt = (c < 122) ? 2 : 1;

        for (int p = 0; p < 8; p++) {
            if (tid == 0)
                while (cload_i(pdone + p) < 128) __builtin_amdgcn_s_sleep(32);
            __syncthreads();
            for (int i = tid; i < 8192; i += 512)
                ldsU[i] = cload_ull(HbU + (size_t)p * 8192 + i);
            __syncthreads();

            f32x4 acc[2][4][2];
            float bdv[2][2];
            const bf16x8* A = (const bf16x8*)ldsA;
#pragma unroll
            for (int t = 0; t < 2; t++) {
                if (t >= nt) break;
                int np = c + 128 * t;
                const bf16x8* B = (const bf16x8*)wdT + (size_t)np * 4096;
#pragma unroll
                for (int mf = 0; mf < 4; mf++)
#pragma unroll
                    for (int nf = 0; nf < 2; nf++) acc[t][mf][nf] = (f32x4){0.f, 0.f, 0.f, 0.f};
#pragma unroll
                for (int ks = 0; ks < 8; ks++) {
                    bf16x8 av[4], bv[2];
#pragma unroll
                    for (int mf = 0; mf < 4; mf++) av[mf] = A[(ks * 8 + wm * 4 + mf) * 64 + l];
#pragma unroll
                    for (int nf = 0; nf < 2; nf++) bv[nf] = B[(ks * 8 + wn * 2 + nf) * 64 + l];
#pragma unroll
                    for (int mf = 0; mf < 4; mf++)
#pragma unroll
                        for (int nf = 0; nf < 2; nf++)
                            acc[t][mf][nf] = __builtin_amdgcn_mfma_f32_16x16x32_bf16(
                                av[mf], bv[nf], acc[t][mf][nf], 0, 0, 0);
                }
#pragma unroll
                for (int nf = 0; nf < 2; nf++)
                    bdv[t][nf] = bd[np * 128 + wn * 32 + nf * 16 + (l & 15)];
#pragma unroll
                for (int mf = 0; mf < 4; mf++) {
#pragma unroll
                    for (int reg = 0; reg < 4; reg++) {
                        float v = __expf(acc[t][mf][0][reg] + bdv[t][0]) +
                                  __expf(acc[t][mf][1][reg] + bdv[t][1]);
                        v += __shfl_xor(v, 1);
                        v += __shfl_xor(v, 2);
                        v += __shfl_xor(v, 4);
                        v += __shfl_xor(v, 8);
                        if ((l & 15) == 0) {
                            int row = wm * 64 + mf * 16 + (l >> 4) * 4 + reg;
                            if (t == 0) sums[row * 4 + wn] = v;
                            else sums[row * 4 + wn] += v;
                        }
                    }
                }
            }
            __syncthreads();
            if (tid < 128) {
                float s = sums[tid * 4] + sums[tid * 4 + 1] + sums[tid * 4 + 2] + sums[tid * 4 + 3];
                atomicAdd(&rs[p * 128 + tid], s);
            }
            asm volatile("s_waitcnt vmcnt(0)" ::: "memory");
            __syncthreads();
            if (tid == 0) {
                __hip_atomic_fetch_add(done0 + p, 1, __ATOMIC_RELAXED, __HIP_MEMORY_SCOPE_AGENT);
                while (cload_i(done0 + p) < 128) __builtin_amdgcn_s_sleep(8);
            }
            __syncthreads();

            float rinv[4][4];
#pragma unroll
            for (int mf = 0; mf < 4; mf++)
#pragma unroll
                for (int reg = 0; reg < 4; reg++)
                    rinv[mf][reg] =
                        1.0f / cload(&rs[p * 128 + wm * 64 + mf * 16 + (l >> 4) * 4 + reg]);
#pragma unroll
            for (int t = 0; t < 2; t++) {
                if (t >= nt) break;
                int np = c + 128 * t;
#pragma unroll
                for (int mf = 0; mf < 4; mf++) {
#pragma unroll
                    for (int nf = 0; nf < 2; nf++) {
                        int col = np * 128 + wn * 32 + nf * 16 + (l & 15);
#pragma unroll
                        for (int reg = 0; reg < 4; reg++) {
                            int rr = p * 128 + wm * 64 + mf * 16 + (l >> 4) * 4 + reg;
                            float pv = __expf(acc[t][mf][nf][reg] + bdv[t][nf]);
                            out[(size_t)((rr & 15) * NT + (rr >> 4)) * NV + col] =
                                pv * rinv[mf][reg];
                        }
                    }
                }
            }
        }
    }
}

extern "C" void kernel_launch(void* const* d_in, const int* in_sizes, int n_in,
                              void* d_out, int out_size, void* d_ws, size_t ws_size,
                              hipStream_t stream) {
    const int* dec = (const int*)d_in[0];
    const float* enc = (const float*)d_in[1];
    const float* h0 = (const float*)d_in[2];
    const float* c0 = (const float*)d_in[3];
    const float* emb = (const float*)d_in[4];
    const float* W1 = (const float*)d_in[5];
    const float* b1 = (const float*)d_in[6];
    const float* W2 = (const float*)d_in[7];
    const float* b2 = (const float*)d_in[8];
    const float* Va = (const float*)d_in[9];
    const float* bV = (const float*)d_in[10];
    const float* Wx = (const float*)d_in[11];
    const float* Wh = (const float*)d_in[12];
    const float* b_lstm = (const float*)d_in[13];
    const float* Wd = (const float*)d_in[14];
    const float* bd = (const float*)d_in[15];
    float* out = (float*)d_out;
    float* ws = (float*)d_ws;

    unsigned short* keysT = (unsigned short*)(ws + OFF_KEYS);
    float* hx = ws + OFF_HX;
    float* ws_rs = ws + OFF_RS;
    int* cnt = (int*)(ws + OFF_CNT);
    unsigned short* Hb = (unsigned short*)(ws + OFF_HB);
    unsigned int* W1h = (unsigned int*)(ws + OFF_W1P);
    float* encWx = ws + OFF_ENCWX;
    float* zemb = ws + OFF_ZEMB;
    unsigned short* wdT = (unsigned short*)(ws + OFF_WDT);

    prologue_kernel<<<5060, 256, 0, stream>>>(dec, enc, emb, W1, W2, b2, Wx, b_lstm, Wd,
                                              ws_rs, cnt, hx, W1h, keysT, encWx, zemb, wdT);

    void* args[] = {(void*)&b1, (void*)&Va, (void*)&bV, (void*)&Wh, (void*)&h0, (void*)&c0,
                    (void*)&keysT, (void*)&W1h, (void*)&encWx, (void*)&zemb, (void*)&hx,
                    (void*)&Hb, (void*)&wdT, (void*)&bd, (void*)&ws_rs,
                    (void*)&cnt, (void*)&out};
    hipLaunchCooperativeKernel((const void*)mega_kernel, dim3(256), dim3(512), args, 0, stream);
}

// Round 18
// 466.149 us; speedup vs baseline: 1.2893x; 1.2893x over previous
//
#include <hip/hip_runtime.h>

// Decoder, B=16, T=64, S=128, D_ENC=512, U=256, V=32000.
// Round 18: R16 producers (p-exchange, 8-way score split) + single merged
// prologue WITHOUT wdtile + consumers tile their OWN wdT panels in their
// preamble (block c converts Wd cols for np=c,c+128 — no cross-block dep),
// hidden under the producers' first ~8 steps.

#define NB 16
#define NT 64
#define NS 128
#define DE 512
#define NU 256
#define NV 32000

// ws layout (floats); total 30.7 MB (<= 34.5 MB proven in R2)
static const size_t OFF_KEYS  = 0;          // keysT bf16 [16][256][128] -> 262144
static const size_t OFF_HX    = 262144;     // hx dbuf [2][16][256] (sign-tag,+2)
static const size_t OFF_PX    = 270336;     // px dbuf [2][16][128] (sign-tag)
static const size_t OFF_RS    = 274432;     // rowsums [1024]
static const size_t OFF_CNT   = 275456;     // pdone[8] @0, done0[8] @32 (128 ints)
static const size_t OFF_HB    = 275584;     // Hb fragment-tiled bf16 -> 131072 fl
static const size_t OFF_W1P   = 406656;     // W1 f16-packed -> 32768
static const size_t OFF_ENCWX = 439424;     // [2048][1024] fp32 -> 2097152
static const size_t OFF_ZEMB  = 2536576;    // [1024][1024] fp32 -> 1048576
static const size_t OFF_WDT   = 3585152;    // wdT bf16 tiled -> 4096000 fl

typedef __attribute__((ext_vector_type(8))) short bf16x8;
typedef __attribute__((ext_vector_type(4))) float f32x4;
typedef __attribute__((ext_vector_type(2))) _Float16 f16x2;

__device__ __forceinline__ float bf2f(unsigned int us) { return __uint_as_float(us << 16); }
__device__ __forceinline__ unsigned short f2bf(float f) {
    unsigned int u = __float_as_uint(f);
    return (unsigned short)((u + 0x7fffu + ((u >> 16) & 1u)) >> 16);
}
__device__ __forceinline__ float rcp_fast(float x) { return __builtin_amdgcn_rcpf(x); }
__device__ __forceinline__ float sigm(float x) { return rcp_fast(1.0f + __expf(-x)); }
__device__ __forceinline__ float tanh1(float x) {
    float e = __expf(2.0f * x);
    return 1.0f - 2.0f * rcp_fast(e + 1.0f);
}
__device__ __forceinline__ void cstore(float* p, float v) {
    __hip_atomic_store(p, v, __ATOMIC_RELAXED, __HIP_MEMORY_SCOPE_AGENT);
}
__device__ __forceinline__ float cload(const float* p) {
    return __hip_atomic_load(p, __ATOMIC_RELAXED, __HIP_MEMORY_SCOPE_AGENT);
}
__device__ __forceinline__ unsigned long long cload_ull(const unsigned long long* p) {
    return __hip_atomic_load(p, __ATOMIC_RELAXED, __HIP_MEMORY_SCOPE_AGENT);
}
__device__ __forceinline__ int cload_i(const int* p) {
    return __hip_atomic_load(p, __ATOMIC_RELAXED, __HIP_MEMORY_SCOPE_AGENT);
}

#if __has_builtin(__builtin_amdgcn_fdot2)
__device__ __forceinline__ float dot2(f16x2 w, f16x2 h, float a) {
    return __builtin_amdgcn_fdot2(w, h, a, false);
}
#else
__device__ __forceinline__ float dot2(f16x2 w, f16x2 h, float a) {
    return fmaf((float)w.x, (float)h.x, fmaf((float)w.y, (float)h.y, a));
}
#endif

__device__ __forceinline__ float poll_tagged(const float* p, unsigned tag) {
    float raw = cload(p);
    while ((__float_as_uint(raw) >> 31) != tag) {
        __builtin_amdgcn_s_sleep(1);
        raw = cload(p);
    }
    return __builtin_fabsf(raw);
}

// ---------------- fused prologue (no wdtile) ----------------
__launch_bounds__(256)
__global__ void prologue_kernel(const int* __restrict__ dec, const float* __restrict__ enc,
                                const float* __restrict__ emb, const float* __restrict__ W1,
                                const float* __restrict__ W2, const float* __restrict__ b2,
                                const float* __restrict__ Wx, const float* __restrict__ b_lstm,
                                float* __restrict__ rs, int* __restrict__ cnt,
                                float* __restrict__ hx, float* __restrict__ px,
                                unsigned int* __restrict__ W1h, unsigned short* __restrict__ keysT,
                                float* __restrict__ encWx, float* __restrict__ zemb) {
    int blk = blockIdx.x, tid = threadIdx.x;
    if (blk < 4) {
        int i = blk * 256 + tid;
        rs[i] = 0.f;
        if (i < 128) cnt[i] = 0;
    } else if (blk < 52) {
        int idx = (blk - 4) * 256 + tid;
        if (idx < 4096) hx[idx] = 2.0f;
        else if (idx < 8192) hx[idx] = -2.0f;
        else px[idx - 8192] = -1.0f;
    } else if (blk < 180) {
        int id = (blk - 52) * 256 + tid;
        int dp = id >> 8, u = id & 255;
        unsigned short lo = __builtin_bit_cast(unsigned short, (_Float16)W1[(size_t)(2 * dp) * NU + u]);
        unsigned short hi = __builtin_bit_cast(unsigned short, (_Float16)W1[(size_t)(2 * dp + 1) * NU + u]);
        W1h[id] = (unsigned int)lo | ((unsigned int)hi << 16);
    } else if (blk < 308) {
        int bb = (blk - 180) >> 3, sg = (blk - 180) & 7;
        int u = tid;
        float acc[16];
        float bias = b2[u];
#pragma unroll
        for (int r = 0; r < 16; r++) acc[r] = bias;
        const float4* e4 = (const float4*)(enc + ((size_t)bb * NS + sg * 16) * DE);
        const float* wp = W2 + u;
        for (int k4 = 0; k4 < DE / 4; k4++) {
            float w0 = wp[(size_t)(k4 * 4 + 0) * NU];
            float w1 = wp[(size_t)(k4 * 4 + 1) * NU];
            float w2v = wp[(size_t)(k4 * 4 + 2) * NU];
            float w3v = wp[(size_t)(k4 * 4 + 3) * NU];
#pragma unroll
            for (int r = 0; r < 16; r++) {
                float4 e = e4[(size_t)r * (DE / 4) + k4];  // wave-uniform
                acc[r] = fmaf(e.x, w0, fmaf(e.y, w1, fmaf(e.z, w2v, fmaf(e.w, w3v, acc[r]))));
            }
        }
        unsigned int ow[8];
#pragma unroll
        for (int i = 0; i < 8; i++)
            ow[i] = (unsigned int)f2bf(acc[2 * i]) | ((unsigned int)f2bf(acc[2 * i + 1]) << 16);
        uint4* dst = (uint4*)(keysT + ((size_t)bb * NU + u) * NS + sg * 16);
        dst[0] = make_uint4(ow[0], ow[1], ow[2], ow[3]);
        dst[1] = make_uint4(ow[4], ow[5], ow[6], ow[7]);
    } else if (blk < 820) {
        int rg = (blk - 308) >> 2, jq = (blk - 308) & 3;
        int j = jq * 256 + tid;
        float acc[16];
#pragma unroll
        for (int r = 0; r < 16; r++) acc[r] = 0.f;
        const float4* e4 = (const float4*)(enc + (size_t)rg * 16 * DE);
        const float* wp = Wx + j;
        for (int k4 = 0; k4 < DE / 4; k4++) {
            float w0 = wp[(size_t)(k4 * 4 + 0) * 1024];
            float w1 = wp[(size_t)(k4 * 4 + 1) * 1024];
            float w2v = wp[(size_t)(k4 * 4 + 2) * 1024];
            float w3v = wp[(size_t)(k4 * 4 + 3) * 1024];
#pragma unroll
            for (int r = 0; r < 16; r++) {
                float4 e = e4[(size_t)r * (DE / 4) + k4];  // wave-uniform
                acc[r] = fmaf(e.x, w0, fmaf(e.y, w1, fmaf(e.z, w2v, fmaf(e.w, w3v, acc[r]))));
            }
        }
#pragma unroll
        for (int r = 0; r < 16; r++) encWx[(size_t)(rg * 16 + r) * 1024 + j] = acc[r];
    } else {
        int rg = (blk - 820) >> 2, jq = (blk - 820) & 3;
        int j = jq * 256 + tid;
        int tokr[16];
#pragma unroll
        for (int r = 0; r < 16; r++) {
            int row = rg * 16 + r;
            int tok = dec[(row >> 6) * NT + (row & 63)];
            tokr[r] = (tok < 0) ? 0 : (tok >= NV ? NV - 1 : tok);
        }
        float acc[16];
        float bias = b_lstm[j];
#pragma unroll
        for (int r = 0; r < 16; r++) acc[r] = bias;
        const float* wp = Wx + (size_t)512 * 1024 + j;
        for (int k4 = 0; k4 < NU / 4; k4++) {
            float w0 = wp[(size_t)(k4 * 4 + 0) * 1024];
            float w1 = wp[(size_t)(k4 * 4 + 1) * 1024];
            float w2v = wp[(size_t)(k4 * 4 + 2) * 1024];
            float w3v = wp[(size_t)(k4 * 4 + 3) * 1024];
#pragma unroll
            for (int r = 0; r < 16; r++) {
                float4 e = ((const float4*)(emb + (size_t)tokr[r] * NU))[k4];  // uniform
                acc[r] = fmaf(e.x, w0, fmaf(e.y, w1, fmaf(e.z, w2v, fmaf(e.w, w3v, acc[r]))));
            }
        }
#pragma unroll
        for (int r = 0; r < 16; r++) zemb[(size_t)(rg * 16 + r) * 1024 + j] = acc[r];
    }
}

// ---------------- mega: XCD 0-3 producers, XCD 4-7 consumers ----------------
__launch_bounds__(512, 2)
__global__ void mega_kernel(const float* __restrict__ b1, const float* __restrict__ Va,
                            const float* __restrict__ bV, const float* __restrict__ Wh,
                            const float* __restrict__ h0, const float* __restrict__ c0,
                            const unsigned short* __restrict__ keysT,
                            const unsigned int* __restrict__ W1h,
                            const float* __restrict__ encWx, const float* __restrict__ zemb,
                            float* __restrict__ hx, float* __restrict__ px,
                            unsigned short* __restrict__ Hb, unsigned short* __restrict__ wdT,
                            const float* __restrict__ Wd,
                            const float* __restrict__ bd, float* __restrict__ rs,
                            int* __restrict__ cnt, float* __restrict__ out) {
    __shared__ float smem[21504];  // 86 KB: forces 1 block/CU
    int tid = threadIdx.x;
    int blk = blockIdx.x;
    int xcd = blk & 7;
    int slot = blk >> 3;
    int* pdone = cnt;        // [8]
    int* done0 = cnt + 32;   // [8]

    if (xcd < 4) {
        // ================= producer: recurrence gang (XCDs 0-3) =================
        int b = (slot >> 3) * 4 + xcd;   // gang = batch, XCD-local
        int r = slot & 7;

        float* hl = smem;
        _Float16* hf = (_Float16*)(smem + 256);
        float* qred = smem + 384;
        float* qv = smem + 896;
        float* scp = smem + 1152;
        float* attnp = smem + 1664;
        float* zred = smem + 1792;

        int kg = tid >> 7, jl = tid & 127;
        int g = jl >> 5, i32 = jl & 31;
        int j = g * 256 + r * 32 + i32;

        float bV0 = bV[0];
        float c_reg = (tid < 32) ? c0[b * NU + r * 32 + tid] : 0.f;

        float wreg[96];
        {
            const float* ew = encWx + (size_t)b * 128 * 1024 + j;
            const float* wh = Wh + j;
#pragma unroll
            for (int kk = 0; kk < 96; kk++) {
                int k = kg * 96 + kk;
                wreg[kk] = (k < 128) ? ew[(size_t)k * 1024] : wh[(size_t)(k - 128) * 1024];
            }
        }

        for (int it = 0; it < NT; ++it) {
            unsigned tag = (unsigned)((it >> 1) & 1);
            float zpre4[4];
            if (tid < 32) {
#pragma unroll
                for (int gg = 0; gg < 4; gg++)
                    zpre4[gg] = zemb[((size_t)b * NT + it) * 1024 + gg * 256 + r * 32 + tid];
            }
            if (tid < NU) {
                float hv;
                if (it == 0) {
                    hv = h0[b * NU + tid];
                } else {
                    hv = poll_tagged(hx + (size_t)(it & 1) * 4096 + b * NU + tid, tag) - 2.0f;
                }
                hl[tid] = hv;
                hf[tid] = (_Float16)hv;
            }
            __syncthreads();

            {
                int u0 = tid & 255, dh = tid >> 8;
                const unsigned int* wp = W1h + dh * 64 * 256 + u0;
                const f16x2* hp = (const f16x2*)hf + dh * 64;
                float a = 0.f;
#pragma unroll 8
                for (int dp = 0; dp < 64; dp++) {
                    f16x2 wv = __builtin_bit_cast(f16x2, wp[(size_t)dp * 256]);
                    a = dot2(wv, hp[dp], a);
                }
                qred[dh * 256 + u0] = a;
            }
            __syncthreads();
            if (tid < NU) qv[tid] = qred[tid] + qred[256 + tid] + b1[tid];
            __syncthreads();

            {
                int sl = tid & 15, uc = tid >> 4;
                int s = r * 16 + sl;
                const unsigned short* kp = keysT + ((size_t)b * NU + uc * 8) * NS + s;
                float sc = 0.f;
#pragma unroll
                for (int i = 0; i < 8; i++)
                    sc = fmaf(tanh1(qv[uc * 8 + i] + bf2f(kp[(size_t)i * NS])), Va[uc * 8 + i], sc);
                scp[uc * 16 + sl] = sc;
            }
            __syncthreads();
            if (tid < 16) {
                float sum = bV0;
#pragma unroll
                for (int k = 0; k < 32; k++) sum += scp[k * 16 + tid];
                float p = __expf(sum);
                cstore(px + (size_t)(it & 1) * 2048 + b * NS + r * 16 + tid, tag ? -p : p);
            }
            float aH = 0.f;
            if (kg == 1) {
#pragma unroll
                for (int kk = 32; kk < 96; kk++) aH = fmaf(wreg[kk], hl[kk - 32], aH);
            } else if (kg >= 2) {
                int base = kg * 96 - 128;
#pragma unroll
                for (int kk = 0; kk < 96; kk++) aH = fmaf(wreg[kk], hl[base + kk], aH);
            }
            if (tid < 128) {
                attnp[tid] = poll_tagged(px + (size_t)(it & 1) * 2048 + b * NS + tid, tag);
            }
            __syncthreads();
            float tot;
            {
                int lane = tid & 63;
                float v = attnp[lane] + attnp[64 + lane];
#pragma unroll
                for (int off = 32; off >= 1; off >>= 1) v += __shfl_xor(v, off, 64);
                tot = v;
            }
            float aA = 0.f;
            if (kg == 0) {
#pragma unroll
                for (int kk = 0; kk < 96; kk++) aA = fmaf(wreg[kk], attnp[kk], aA);
            } else if (kg == 1) {
#pragma unroll
                for (int kk = 0; kk < 32; kk++) aA = fmaf(wreg[kk], attnp[96 + kk], aA);
            }
            zred[kg * 128 + jl] = aA * rcp_fast(tot) + aH;
            __syncthreads();

            if (tid < 32) {
                float z4[4];
#pragma unroll
                for (int gg = 0; gg < 4; gg++) {
                    int jj = gg * 32 + tid;
                    z4[gg] = zred[jj] + zred[128 + jj] + zred[256 + jj] + zred[384 + jj] + zpre4[gg];
                }
                float cn = sigm(z4[1]) * c_reg + sigm(z4[0]) * tanh1(z4[2]);
                c_reg = cn;
                float hn = sigm(z4[3]) * tanh1(cn);
                int u = r * 32 + tid;
                int rr = it * NB + b;
                int mp = rr >> 7, lr = rr & 127;
                int chunk = ((u >> 5) * 8 + (lr >> 4)) * 64 + ((u >> 3) & 3) * 16 + (lr & 15);
                __hip_atomic_store(&Hb[(size_t)mp * 32768 + chunk * 8 + (u & 7)], f2bf(hn),
                                   __ATOMIC_RELAXED, __HIP_MEMORY_SCOPE_AGENT);
                unsigned ntag = (unsigned)(((it + 1) >> 1) & 1);
                float enc2 = hn + 2.0f;
                cstore(hx + (size_t)((it + 1) & 1) * 4096 + b * NU + u, ntag ? -enc2 : enc2);
            }
            if ((it & 7) == 7 && tid < 64) {
                asm volatile("s_waitcnt vmcnt(0)" ::: "memory");
                if (tid == 0)
                    __hip_atomic_fetch_add(pdone + (it >> 3), 1, __ATOMIC_RELAXED,
                                           __HIP_MEMORY_SCOPE_AGENT);
            }
        }
    } else {
        // ================= consumer: vocab GEMM (XCDs 4-7) =================
        int c = slot * 4 + (xcd - 4);  // 0..127
        float* ldsA = smem;            // 64 KB A panel
        float* sums = smem + 16384;    // [128][4]
        const unsigned long long* HbU = (const unsigned long long*)Hb;
        unsigned long long* ldsU = (unsigned long long*)ldsA;

        int wave = tid >> 6, l = tid & 63;
        int wm = wave >> 2, wn = wave & 3;
        int nt = (c < 122) ? 2 : 1;

        // ---- preamble: tile OWN wdT panels (np = c, c+128) from fp32 Wd ----
        for (int t = 0; t < nt; t++) {
            int np = c + 128 * t;
            for (int il = tid; il < 4096; il += 512) {
                int id = np * 4096 + il;
                int ll = id & 63, c16 = (id >> 6) & 7, ks = (id >> 9) & 7;
                int v = np * 128 + c16 * 16 + (ll & 15);
                int k0 = ks * 32 + (ll >> 4) * 8;
                unsigned int wout[4];
#pragma unroll
                for (int jj = 0; jj < 4; jj++) {
                    unsigned int lo = f2bf(Wd[(size_t)(k0 + 2 * jj) * NV + v]);
                    unsigned int hi = f2bf(Wd[(size_t)(k0 + 2 * jj + 1) * NV + v]);
                    wout[jj] = lo | (hi << 16);
                }
                *(uint4*)(wdT + (size_t)id * 8) = make_uint4(wout[0], wout[1], wout[2], wout[3]);
            }
        }
        __syncthreads();

        for (int p = 0; p < 8; p++) {
            if (tid == 0)
                while (cload_i(pdone + p) < 128) __builtin_amdgcn_s_sleep(32);
            __syncthreads();
            for (int i = tid; i < 8192; i += 512)
                ldsU[i] = cload_ull(HbU + (size_t)p * 8192 + i);
            __syncthreads();

            f32x4 acc[2][4][2];
            float bdv[2][2];
            const bf16x8* A = (const bf16x8*)ldsA;
#pragma unroll
            for (int t = 0; t < 2; t++) {
                if (t >= nt) break;
                int np = c + 128 * t;
                const bf16x8* B = (const bf16x8*)wdT + (size_t)np * 4096;
#pragma unroll
                for (int mf = 0; mf < 4; mf++)
#pragma unroll
                    for (int nf = 0; nf < 2; nf++) acc[t][mf][nf] = (f32x4){0.f, 0.f, 0.f, 0.f};
#pragma unroll
                for (int ks = 0; ks < 8; ks++) {
                    bf16x8 av[4], bv[2];
#pragma unroll
                    for (int mf = 0; mf < 4; mf++) av[mf] = A[(ks * 8 + wm * 4 + mf) * 64 + l];
#pragma unroll
                    for (int nf = 0; nf < 2; nf++) bv[nf] = B[(ks * 8 + wn * 2 + nf) * 64 + l];
#pragma unroll
                    for (int mf = 0; mf < 4; mf++)
#pragma unroll
                        for (int nf = 0; nf < 2; nf++)
                            acc[t][mf][nf] = __builtin_amdgcn_mfma_f32_16x16x32_bf16(
                                av[mf], bv[nf], acc[t][mf][nf], 0, 0, 0);
                }
#pragma unroll
                for (int nf = 0; nf < 2; nf++)
                    bdv[t][nf] = bd[np * 128 + wn * 32 + nf * 16 + (l & 15)];
#pragma unroll
                for (int mf = 0; mf < 4; mf++) {
#pragma unroll
                    for (int reg = 0; reg < 4; reg++) {
                        float v = __expf(acc[t][mf][0][reg] + bdv[t][0]) +
                                  __expf(acc[t][mf][1][reg] + bdv[t][1]);
                        v += __shfl_xor(v, 1);
                        v += __shfl_xor(v, 2);
                        v += __shfl_xor(v, 4);
                        v += __shfl_xor(v, 8);
                        if ((l & 15) == 0) {
                            int row = wm * 64 + mf * 16 + (l >> 4) * 4 + reg;
                            if (t == 0) sums[row * 4 + wn] = v;
                            else sums[row * 4 + wn] += v;
                        }
                    }
                }
            }
            __syncthreads();
            if (tid < 128) {
                float s = sums[tid * 4] + sums[tid * 4 + 1] + sums[tid * 4 + 2] + sums[tid * 4 + 3];
                atomicAdd(&rs[p * 128 + tid], s);
            }
            asm volatile("s_waitcnt vmcnt(0)" ::: "memory");
            __syncthreads();
            if (tid == 0) {
                __hip_atomic_fetch_add(done0 + p, 1, __ATOMIC_RELAXED, __HIP_MEMORY_SCOPE_AGENT);
                while (cload_i(done0 + p) < 128) __builtin_amdgcn_s_sleep(8);
            }
            __syncthreads();

            float rinv[4][4];
#pragma unroll
            for (int mf = 0; mf < 4; mf++)
#pragma unroll
                for (int reg = 0; reg < 4; reg++)
                    rinv[mf][reg] =
                        1.0f / cload(&rs[p * 128 + wm * 64 + mf * 16 + (l >> 4) * 4 + reg]);
#pragma unroll
            for (int t = 0; t < 2; t++) {
                if (t >= nt) break;
                int np = c + 128 * t;
#pragma unroll
                for (int mf = 0; mf < 4; mf++) {
#pragma unroll
                    for (int nf = 0; nf < 2; nf++) {
                        int col = np * 128 + wn * 32 + nf * 16 + (l & 15);
#pragma unroll
                        for (int reg = 0; reg < 4; reg++) {
                            int rr = p * 128 + wm * 64 + mf * 16 + (l >> 4) * 4 + reg;
                            float pv = __expf(acc[t][mf][nf][reg] + bdv[t][nf]);
                            out[(size_t)((rr & 15) * NT + (rr >> 4)) * NV + col] =
                                pv * rinv[mf][reg];
                        }
                    }
                }
            }
        }
    }
}

extern "C" void kernel_launch(void* const* d_in, const int* in_sizes, int n_in,
                              void* d_out, int out_size, void* d_ws, size_t ws_size,
                              hipStream_t stream) {
    const int* dec = (const int*)d_in[0];
    const float* enc = (const float*)d_in[1];
    const float* h0 = (const float*)d_in[2];
    const float* c0 = (const float*)d_in[3];
    const float* emb = (const float*)d_in[4];
    const float* W1 = (const float*)d_in[5];
    const float* b1 = (const float*)d_in[6];
    const float* W2 = (const float*)d_in[7];
    const float* b2 = (const float*)d_in[8];
    const float* Va = (const float*)d_in[9];
    const float* bV = (const float*)d_in[10];
    const float* Wx = (const float*)d_in[11];
    const float* Wh = (const float*)d_in[12];
    const float* b_lstm = (const float*)d_in[13];
    const float* Wd = (const float*)d_in[14];
    const float* bd = (const float*)d_in[15];
    float* out = (float*)d_out;
    float* ws = (float*)d_ws;

    unsigned short* keysT = (unsigned short*)(ws + OFF_KEYS);
    float* hx = ws + OFF_HX;
    float* px = ws + OFF_PX;
    float* ws_rs = ws + OFF_RS;
    int* cnt = (int*)(ws + OFF_CNT);
    unsigned short* Hb = (unsigned short*)(ws + OFF_HB);
    unsigned int* W1h = (unsigned int*)(ws + OFF_W1P);
    float* encWx = ws + OFF_ENCWX;
    float* zemb = ws + OFF_ZEMB;
    unsigned short* wdT = (unsigned short*)(ws + OFF_WDT);

    prologue_kernel<<<1076, 256, 0, stream>>>(dec, enc, emb, W1, W2, b2, Wx, b_lstm,
                                              ws_rs, cnt, hx, px, W1h, keysT, encWx, zemb);

    void* args[] = {(void*)&b1, (void*)&Va, (void*)&bV, (void*)&Wh, (void*)&h0, (void*)&c0,
                    (void*)&keysT, (void*)&W1h, (void*)&encWx, (void*)&zemb, (void*)&hx,
                    (void*)&px, (void*)&Hb, (void*)&wdT, (void*)&Wd, (void*)&bd, (void*)&ws_rs,
                    (void*)&cnt, (void*)&out};
    hipLaunchCooperativeKernel((const void*)mega_kernel, dim3(256), dim3(512), args, 0, stream);
}